// Round 2
// 204.668 us; speedup vs baseline: 1.0090x; 1.0090x over previous
//
#include <hip/hip_runtime.h>

// EdgeLoss: loss = mean|Sobel_x(d)| + mean|Sobel_y(d)|, d = gray(sr) - gray(hr)
// B=32, C=3, H=W=512. 201 MB mandatory read.
// R6: non-temporal loads broke the ~3 TB/s cache-path wall (HBM-direct).
// R7: hoist all 30 loads/thread branch-free, (256,4) -> 128 VGPR cap.
// R8: NT bypasses L2, so the 2 halo rows per 8-row strip were fetched from
// HBM twice (25% over-fetch, ~252 MB vs 201 MB mandatory). Shared rows are
// exactly gr%8 in {0,7}; in Phase-A indexing r = 2i+(tid>>7), so iterations
// i=0 (r=0,1) and i=4 (r=8,9) cover all shared rows at COMPILE TIME. Those
// use regular cached loads -> vertically-adjacent strips (same XCD via the
// swizzle, co-resident within +-8 blockIdx) L2-hit each other's fetch.
// Interior rows i=1..3 stay NT. Predicted: fetch ~206 MB, kernel ~37->~31 us.
// R9: identical resubmit — R8's bench was an infra failure (container), not
// a kernel result.

typedef float floatx4 __attribute__((ext_vector_type(4)));

#define TH 8            // output rows per block
#define TILE_ROWS 10    // +2 halo rows
#define RS 520          // row stride (floats); data cols 4..515, zero pads 3 & 516

__global__ __launch_bounds__(256, 4)
void edge_loss_fused(const float* __restrict__ sr, const float* __restrict__ hr,
                     float* __restrict__ out) {
    __shared__ float tile[TILE_ROWS][RS];
    const int tid = threadIdx.x;
    // XCD-contiguous swizzle: adjacent strips (shared halo) on one XCD's L2.
    const int gs    = (blockIdx.x & 7) * 256 + (blockIdx.x >> 3);  // 0..2047
    const int img   = gs >> 6;
    const int strip = gs & 63;
    const int row0  = strip * TH;

    if (tid < TILE_ROWS) { tile[tid][3] = 0.f; tile[tid][516] = 0.f; }

    const size_t imgBase = (size_t)img * 786432;
    const float* __restrict__ s0p = sr + imgBase;
    const float* __restrict__ s1p = sr + imgBase + 262144;
    const float* __restrict__ s2p = sr + imgBase + 524288;
    const float* __restrict__ h0p = hr + imgBase;
    const float* __restrict__ h1p = hr + imgBase + 262144;
    const float* __restrict__ h2p = hr + imgBase + 524288;

    // Phase A: issue ALL 30 loads (no runtime branches -> nothing blocks issue).
    // i==0 / i==4 touch rows shared with vertical neighbors -> cached loads
    // (L2-shared, fetched once from HBM). i==1..3 are exclusive -> NT.
    floatx4 R0[5], G0[5], B0[5], R1[5], G1[5], B1[5];
    float wgt[5];
    #pragma unroll
    for (int i = 0; i < 5; ++i) {
        const int idx = tid + (i << 8);
        const int r   = idx >> 7;           // tile row 0..9 (wave-uniform)
        const int x4  = (idx & 127) << 2;   // col 0,4,...,508
        const int gr  = row0 - 1 + r;       // global row (-1..512)
        const int grc = min(max(gr, 0), 511);
        wgt[i] = (gr == grc) ? 1.f : 0.f;   // zero out clamped halo rows
        const int off = grc * 512 + x4;
        if (i == 0 || i == 4) {             // compile-time: shared rows, cached
            R0[i] = *(const floatx4*)(s0p + off);
            G0[i] = *(const floatx4*)(s1p + off);
            B0[i] = *(const floatx4*)(s2p + off);
            R1[i] = *(const floatx4*)(h0p + off);
            G1[i] = *(const floatx4*)(h1p + off);
            B1[i] = *(const floatx4*)(h2p + off);
        } else {                            // exclusive rows, HBM-direct
            R0[i] = __builtin_nontemporal_load((const floatx4*)(s0p + off));
            G0[i] = __builtin_nontemporal_load((const floatx4*)(s1p + off));
            B0[i] = __builtin_nontemporal_load((const floatx4*)(s2p + off));
            R1[i] = __builtin_nontemporal_load((const floatx4*)(h0p + off));
            G1[i] = __builtin_nontemporal_load((const floatx4*)(h1p + off));
            B1[i] = __builtin_nontemporal_load((const floatx4*)(h2p + off));
        }
    }
    // Phase B: luma-diff + single 16B-aligned ds_write per group.
    #pragma unroll
    for (int i = 0; i < 5; ++i) {
        const int idx = tid + (i << 8);
        const int r   = idx >> 7;
        const int x4  = (idx & 127) << 2;
        floatx4 d;
        d.x = wgt[i] * (0.2989f*(R0[i].x-R1[i].x) + 0.587f*(G0[i].x-G1[i].x) + 0.114f*(B0[i].x-B1[i].x));
        d.y = wgt[i] * (0.2989f*(R0[i].y-R1[i].y) + 0.587f*(G0[i].y-G1[i].y) + 0.114f*(B0[i].y-B1[i].y));
        d.z = wgt[i] * (0.2989f*(R0[i].z-R1[i].z) + 0.587f*(G0[i].z-G1[i].z) + 0.114f*(B0[i].z-B1[i].z));
        d.w = wgt[i] * (0.2989f*(R0[i].w-R1[i].w) + 0.587f*(G0[i].w-G1[i].w) + 0.114f*(B0[i].w-B1[i].w));
        *(floatx4*)&tile[r][4 + x4] = d;    // (4+x4)*4B : 16B aligned
    }
    __syncthreads();

    // 4 groups of 4 output pixels per thread: 8 rows x 128 groups.
    // Output group base col x4 needs input cols x4-1..x4+4 = padded x4+3..x4+8.
    float acc = 0.f;
    #pragma unroll
    for (int i = 0; i < 4; ++i) {
        const int g  = tid + (i << 8);
        const int r  = g >> 7;
        const int x4 = (g & 127) << 2;
        const float* A  = &tile[r][x4 + 3];
        const float* Bc = &tile[r + 1][x4 + 3];
        const float* Cc = &tile[r + 2][x4 + 3];
        const float a0=A[0],a1=A[1],a2=A[2],a3=A[3],a4=A[4],a5=A[5];
        const float b0=Bc[0],b1=Bc[1],b2=Bc[2],b3=Bc[3],b4=Bc[4],b5=Bc[5];
        const float c0=Cc[0],c1=Cc[1],c2=Cc[2],c3=Cc[3],c4=Cc[4],c5=Cc[5];
        const float s0=a0+2.f*b0+c0, s1=a1+2.f*b1+c1, s2=a2+2.f*b2+c2,
                    s3=a3+2.f*b3+c3, s4=a4+2.f*b4+c4, s5=a5+2.f*b5+c5;
        acc += fabsf(s0 - s2) + fabsf(s1 - s3) + fabsf(s2 - s4) + fabsf(s3 - s5);
        acc += fabsf((a0 + 2.f*a1 + a2) - (c0 + 2.f*c1 + c2));
        acc += fabsf((a1 + 2.f*a2 + a3) - (c1 + 2.f*c2 + c3));
        acc += fabsf((a2 + 2.f*a3 + a4) - (c2 + 2.f*c3 + c4));
        acc += fabsf((a3 + 2.f*a4 + a5) - (c3 + 2.f*c4 + c5));
    }

    #pragma unroll
    for (int o = 32; o > 0; o >>= 1) acc += __shfl_down(acc, o, 64);
    __shared__ float wsum[4];
    if ((tid & 63) == 0) wsum[tid >> 6] = acc;
    __syncthreads();
    if (tid == 0) {
        const float s = (wsum[0] + wsum[1] + wsum[2] + wsum[3]) * (1.0f / 8388608.0f);
        atomicAdd(out, s);
    }
}

extern "C" void kernel_launch(void* const* d_in, const int* in_sizes, int n_in,
                              void* d_out, int out_size, void* d_ws, size_t ws_size,
                              hipStream_t stream) {
    const float* sr = (const float*)d_in[0];
    const float* hr = (const float*)d_in[1];
    float* out = (float*)d_out;
    (void)hipMemsetAsync(out, 0, sizeof(float), stream);
    edge_loss_fused<<<dim3(32 * 64), dim3(256), 0, stream>>>(sr, hr, out);
}